// Round 14
// baseline (124.732 us; speedup 1.0000x reference)
//
#include <hip/hip_runtime.h>

// ---------------------------------------------------------------------------
// GCN 2-layer forward, 6 dispatches:
//   memset        : cursors = 0
//   k_build_gemm1 : 1024 thr/block. blocks [0,B1) = bucket binning (LDS hist
//                   -> 1 global atomic per bucket -> padded scatter), edges
//                   register-cached (single read); blocks [B1,..) = MFMA gemm1
//                   hu_bf16 = bf16(X@W1 + b1)  (UNSCALED -> no build dep)
//   k_reorder     : per-bucket LDS sort -> padded CSR, binned register-cached
//   k_gather64    : out1 = relu(dis_i*(dis_i*hu_i + sum_j dis_j*hu_j))
//   k_gemm2_mfma  : h2s_bf16 = bf16((out1@W2 + b2)*dis)
//   k_gather40    : out2 = dis_i*(h2s_i + sum_j h2s_j)  (60-lane, 3 groups)
// ---------------------------------------------------------------------------

#define B1 256          // build blocks
#define BT 1024         // build/gemm1 merged kernel block size
#define GROWS 512       // gemm1 rows per block (16 waves x 32 rows)
#define BUCK_SHIFT 6    // 64 nodes per bucket
#define MAXBUCK 4096    // LDS cap on bucket count
#define CAP 4096        // padded slots per bucket (fill ~2250 max)
#define WK 136          // gemm1 LDS K stride (ushorts)
#define WK2 72          // gemm2 LDS K stride (ushorts)

typedef float f32x4 __attribute__((ext_vector_type(4)));
typedef short bf16x8 __attribute__((ext_vector_type(8)));

union Frag { unsigned int u[4]; bf16x8 v; };

__device__ __forceinline__ unsigned int cvt_pk_bf16(float a, float b) {
    unsigned int r;
    asm("v_cvt_pk_bf16_f32 %0, %1, %2" : "=v"(r) : "v"(a), "v"(b));
    return r;  // low16 = bf16(a), high16 = bf16(b), RNE
}

__device__ __forceinline__ float bf_lo(unsigned int u) {
    return __uint_as_float(u << 16);
}
__device__ __forceinline__ float bf_hi(unsigned int u) {
    return __uint_as_float(u & 0xffff0000u);
}

__device__ __forceinline__ bf16x8 ld_frag(const unsigned short* p) {
    uint4 t = *reinterpret_cast<const uint4*>(p);
    Frag f; f.u[0] = t.x; f.u[1] = t.y; f.u[2] = t.z; f.u[3] = t.w;
    return f.v;
}

__device__ __forceinline__ void make_frags(const float4 a, const float4 b,
                                           bf16x8& hi8, bf16x8& lo8) {
    Frag hi, lo;
    hi.u[0] = cvt_pk_bf16(a.x, a.y);
    hi.u[1] = cvt_pk_bf16(a.z, a.w);
    hi.u[2] = cvt_pk_bf16(b.x, b.y);
    hi.u[3] = cvt_pk_bf16(b.z, b.w);
    lo.u[0] = cvt_pk_bf16(a.x - __uint_as_float(hi.u[0] << 16),
                          a.y - __uint_as_float(hi.u[0] & 0xffff0000u));
    lo.u[1] = cvt_pk_bf16(a.z - __uint_as_float(hi.u[1] << 16),
                          a.w - __uint_as_float(hi.u[1] & 0xffff0000u));
    lo.u[2] = cvt_pk_bf16(b.x - __uint_as_float(hi.u[2] << 16),
                          b.y - __uint_as_float(hi.u[2] & 0xffff0000u));
    lo.u[3] = cvt_pk_bf16(b.z - __uint_as_float(hi.u[3] << 16),
                          b.w - __uint_as_float(hi.u[3] & 0xffff0000u));
    hi8 = hi.v; lo8 = lo.v;
}

// ---------------------------------------------------------------------------
// Merged build + gemm1, 1024 threads.
// ---------------------------------------------------------------------------
__global__ __launch_bounds__(BT) void k_build_gemm1(
        const int* __restrict__ src, const int* __restrict__ dst,
        int* __restrict__ cursors, unsigned int* __restrict__ binned,
        const float* __restrict__ X, const float* __restrict__ W1,
        const float* __restrict__ b1, unsigned short* __restrict__ hub,
        int E, int nbuck, int chunk, int N) {
    __shared__ __align__(16) char smem[34816];  // max(2*MAXBUCK*4, 2*64*WK*2)

    if (blockIdx.x < B1) {
        // ---------------- build path ----------------
        int* lh    = (int*)smem;
        int* lbase = lh + MAXBUCK;
        for (int i = threadIdx.x; i < nbuck; i += BT) lh[i] = 0;
        __syncthreads();
        int e0 = blockIdx.x * chunk;
        int e1 = min(e0 + chunk, E);
        // register-cache up to 4 edges/thread (chunk <= 4*BT for E<=~1M@B1=256)
        int es[4], eds[4];
        #pragma unroll
        for (int i = 0; i < 4; ++i) {
            int e = e0 + threadIdx.x + i * BT;
            if (e < e1) {
                int s = src[e], d = dst[e];
                es[i] = s; eds[i] = d;
                atomicAdd(&lh[s >> BUCK_SHIFT], 1);
                atomicAdd(&lh[d >> BUCK_SHIFT], 1);
            }
        }
        for (int e = e0 + threadIdx.x + 4 * BT; e < e1; e += BT) {  // safety
            atomicAdd(&lh[src[e] >> BUCK_SHIFT], 1);
            atomicAdd(&lh[dst[e] >> BUCK_SHIFT], 1);
        }
        __syncthreads();
        for (int i = threadIdx.x; i < nbuck; i += BT) {
            int c = lh[i];
            int rel = (c > 0) ? atomicAdd(&cursors[i], c) : 0;
            lbase[i] = i * CAP + rel;
            lh[i] = 0;  // reuse as intra-block write cursor
        }
        __syncthreads();
        #pragma unroll
        for (int i = 0; i < 4; ++i) {
            int e = e0 + threadIdx.x + i * BT;
            if (e < e1) {
                unsigned int s = (unsigned int)es[i];
                unsigned int d = (unsigned int)eds[i];
                int bs = s >> BUCK_SHIFT, bd = d >> BUCK_SHIFT;
                int p = lbase[bs] + atomicAdd(&lh[bs], 1);
                if (p < ((bs + 1) << 12)) binned[p] = (s << 16) | d;
                int q = lbase[bd] + atomicAdd(&lh[bd], 1);
                if (q < ((bd + 1) << 12)) binned[q] = (d << 16) | s;
            }
        }
        for (int e = e0 + threadIdx.x + 4 * BT; e < e1; e += BT) {  // safety
            unsigned int s = (unsigned int)src[e];
            unsigned int d = (unsigned int)dst[e];
            int bs = s >> BUCK_SHIFT, bd = d >> BUCK_SHIFT;
            int p = lbase[bs] + atomicAdd(&lh[bs], 1);
            if (p < ((bs + 1) << 12)) binned[p] = (s << 16) | d;
            int q = lbase[bd] + atomicAdd(&lh[bd], 1);
            if (q < ((bd + 1) << 12)) binned[q] = (d << 16) | s;
        }
        return;
    }

    // ---------------- gemm1 path (split-bf16 MFMA, unscaled) ----------------
    unsigned short* sWhi = (unsigned short*)smem;
    unsigned short* sWlo = sWhi + 64 * WK;
    for (int i = threadIdx.x; i < 128 * 64; i += BT) {
        int c = i >> 7;      // 0..63
        int k = i & 127;     // 0..127
        float w = W1[(size_t)k * 64 + c];
        unsigned int hb = cvt_pk_bf16(w, 0.0f) & 0xffffu;
        float hf = __uint_as_float(hb << 16);
        unsigned int lb = cvt_pk_bf16(w - hf, 0.0f) & 0xffffu;
        sWhi[c * WK + k] = (unsigned short)hb;
        sWlo[c * WK + k] = (unsigned short)lb;
    }
    __syncthreads();

    const int lane = threadIdx.x & 63;
    const int wid  = threadIdx.x >> 6;      // 0..15
    const int ridx = lane & 15;
    const int kgrp = lane >> 4;
    const int r0 = (blockIdx.x - B1) * GROWS + wid * 32;

    f32x4 acc[2][4] = {};

    #pragma unroll
    for (int ks = 0; ks < 4; ++ks) {
        const int ka = ks * 32 + kgrp * 8;
        int ra0 = min(r0 + ridx, N - 1);
        int ra1 = min(r0 + 16 + ridx, N - 1);
        const float4* pa0 = (const float4*)(X + (size_t)ra0 * 128 + ka);
        const float4* pa1 = (const float4*)(X + (size_t)ra1 * 128 + ka);
        float4 a0a = pa0[0], a0b = pa0[1];
        float4 a1a = pa1[0], a1b = pa1[1];
        bf16x8 a0hi, a0lo, a1hi, a1lo;
        make_frags(a0a, a0b, a0hi, a0lo);
        make_frags(a1a, a1b, a1hi, a1lo);
        #pragma unroll
        for (int ct = 0; ct < 4; ++ct) {
            const int cbase = (ct * 16 + ridx) * WK + ka;
            bf16x8 bh = ld_frag(sWhi + cbase);
            bf16x8 bl = ld_frag(sWlo + cbase);
            acc[0][ct] = __builtin_amdgcn_mfma_f32_16x16x32_bf16(a0hi, bh, acc[0][ct], 0, 0, 0);
            acc[0][ct] = __builtin_amdgcn_mfma_f32_16x16x32_bf16(a0lo, bh, acc[0][ct], 0, 0, 0);
            acc[0][ct] = __builtin_amdgcn_mfma_f32_16x16x32_bf16(a0hi, bl, acc[0][ct], 0, 0, 0);
            acc[1][ct] = __builtin_amdgcn_mfma_f32_16x16x32_bf16(a1hi, bh, acc[1][ct], 0, 0, 0);
            acc[1][ct] = __builtin_amdgcn_mfma_f32_16x16x32_bf16(a1lo, bh, acc[1][ct], 0, 0, 0);
            acc[1][ct] = __builtin_amdgcn_mfma_f32_16x16x32_bf16(a1hi, bl, acc[1][ct], 0, 0, 0);
        }
    }

    float bias[4];
    #pragma unroll
    for (int ct = 0; ct < 4; ++ct) bias[ct] = b1[ct * 16 + ridx];

    #pragma unroll
    for (int rt = 0; rt < 2; ++rt) {
        int rb = r0 + rt * 16 + kgrp * 4;
        #pragma unroll
        for (int reg = 0; reg < 4; ++reg) {
            int r = rb + reg;
            if (r < N) {
                #pragma unroll
                for (int ct = 0; ct < 4; ++ct) {
                    float v = acc[rt][ct][reg] + bias[ct];
                    hub[(size_t)r * 64 + ct * 16 + ridx] =
                        (unsigned short)(cvt_pk_bf16(v, 0.0f) & 0xffffu);
                }
            }
        }
    }
}

// Per-bucket: binned -> node-grouped ushort adj; binned register-cached
// (single global read). offs/ends absolute, dis = rsqrt(1+deg).
__global__ __launch_bounds__(256) void k_reorder(const unsigned int* __restrict__ binned,
                                                 const int* __restrict__ cursors,
                                                 unsigned short* __restrict__ adj,
                                                 int* __restrict__ offs,
                                                 int* __restrict__ ends,
                                                 float* __restrict__ dis,
                                                 int N, int nbuck) {
    __shared__ int cnt[64];
    __shared__ int cur[64];
    __shared__ unsigned short stage[CAP];
    int b = blockIdx.x;
    int start = b * CAP;
    int fill = cursors[b]; if (fill > CAP) fill = CAP;
    int end = start + fill;
    if (threadIdx.x < 64) cnt[threadIdx.x] = 0;
    __syncthreads();
    // register-cache: CAP/256 = 16 entries max per thread, static unroll
    unsigned int vv[16];
    #pragma unroll
    for (int i = 0; i < 16; ++i) {
        int idx = start + threadIdx.x + i * 256;
        if (idx < end) {
            unsigned int v = binned[idx];
            vv[i] = v;
            atomicAdd(&cnt[(v >> 16) & 63], 1);
        }
    }
    __syncthreads();
    if (threadIdx.x == 0) {
        int run = 0;
        for (int l = 0; l < 64; ++l) { cur[l] = run; run += cnt[l]; }
    }
    __syncthreads();
    if (threadIdx.x < 64) {
        int node = (b << BUCK_SHIFT) + threadIdx.x;
        if (node < N) {
            int o = start + cur[threadIdx.x];
            offs[node] = o;
            ends[node] = o + cnt[threadIdx.x];
            dis[node]  = rsqrtf(1.0f + (float)cnt[threadIdx.x]);
        }
    }
    __syncthreads();
    #pragma unroll
    for (int i = 0; i < 16; ++i) {
        int idx = start + threadIdx.x + i * 256;
        if (idx < end) {
            unsigned int v = vv[i];
            int nl = (v >> 16) & 63;
            int p = atomicAdd(&cur[nl], 1);
            stage[p] = (unsigned short)(v & 0xffffu);
        }
    }
    __syncthreads();
    for (int i = threadIdx.x; i < fill; i += 256)
        adj[start + i] = stage[i];
}

// out1_i = relu(dis_i*(dis_i*hu_i + sum_j dis_j*hu_j)); wave per node.
__global__ __launch_bounds__(256) void k_gather64(const unsigned int* __restrict__ hsu,
                                                  const unsigned short* __restrict__ adj,
                                                  const int* __restrict__ offs,
                                                  const int* __restrict__ ends,
                                                  const float* __restrict__ dis,
                                                  float* __restrict__ out1, int N) {
    int node = (blockIdx.x * 256 + threadIdx.x) >> 6;
    if (node >= N) return;
    int lane = threadIdx.x & 63;
    int half = lane >> 5;
    int c2 = lane & 31;
    int k   = offs[node];
    int end = ends[node];
    float acc0 = 0.f, acc1 = 0.f;
    for (; k + 16 <= end; k += 16) {
        int j0 = adj[k +  0 + half], j1 = adj[k +  2 + half];
        int j2 = adj[k +  4 + half], j3 = adj[k +  6 + half];
        int j4 = adj[k +  8 + half], j5 = adj[k + 10 + half];
        int j6 = adj[k + 12 + half], j7 = adj[k + 14 + half];
        float d0 = dis[j0], d1 = dis[j1], d2 = dis[j2], d3 = dis[j3];
        float d4 = dis[j4], d5 = dis[j5], d6 = dis[j6], d7 = dis[j7];
        unsigned int u0 = hsu[(size_t)j0 * 32 + c2];
        unsigned int u1 = hsu[(size_t)j1 * 32 + c2];
        unsigned int u2 = hsu[(size_t)j2 * 32 + c2];
        unsigned int u3 = hsu[(size_t)j3 * 32 + c2];
        unsigned int u4 = hsu[(size_t)j4 * 32 + c2];
        unsigned int u5 = hsu[(size_t)j5 * 32 + c2];
        unsigned int u6 = hsu[(size_t)j6 * 32 + c2];
        unsigned int u7 = hsu[(size_t)j7 * 32 + c2];
        acc0 = fmaf(d0, bf_lo(u0), acc0); acc1 = fmaf(d0, bf_hi(u0), acc1);
        acc0 = fmaf(d1, bf_lo(u1), acc0); acc1 = fmaf(d1, bf_hi(u1), acc1);
        acc0 = fmaf(d2, bf_lo(u2), acc0); acc1 = fmaf(d2, bf_hi(u2), acc1);
        acc0 = fmaf(d3, bf_lo(u3), acc0); acc1 = fmaf(d3, bf_hi(u3), acc1);
        acc0 = fmaf(d4, bf_lo(u4), acc0); acc1 = fmaf(d4, bf_hi(u4), acc1);
        acc0 = fmaf(d5, bf_lo(u5), acc0); acc1 = fmaf(d5, bf_hi(u5), acc1);
        acc0 = fmaf(d6, bf_lo(u6), acc0); acc1 = fmaf(d6, bf_hi(u6), acc1);
        acc0 = fmaf(d7, bf_lo(u7), acc0); acc1 = fmaf(d7, bf_hi(u7), acc1);
    }
    for (; k + 8 <= end; k += 8) {
        int j0 = adj[k + 0 + half], j1 = adj[k + 2 + half];
        int j2 = adj[k + 4 + half], j3 = adj[k + 6 + half];
        float d0 = dis[j0], d1 = dis[j1], d2 = dis[j2], d3 = dis[j3];
        unsigned int u0 = hsu[(size_t)j0 * 32 + c2];
        unsigned int u1 = hsu[(size_t)j1 * 32 + c2];
        unsigned int u2 = hsu[(size_t)j2 * 32 + c2];
        unsigned int u3 = hsu[(size_t)j3 * 32 + c2];
        acc0 = fmaf(d0, bf_lo(u0), acc0); acc1 = fmaf(d0, bf_hi(u0), acc1);
        acc0 = fmaf(d1, bf_lo(u1), acc0); acc1 = fmaf(d1, bf_hi(u1), acc1);
        acc0 = fmaf(d2, bf_lo(u2), acc0); acc1 = fmaf(d2, bf_hi(u2), acc1);
        acc0 = fmaf(d3, bf_lo(u3), acc0); acc1 = fmaf(d3, bf_hi(u3), acc1);
    }
    for (; k + 2 <= end; k += 2) {
        int j = adj[k + half];
        float d = dis[j];
        unsigned int u = hsu[(size_t)j * 32 + c2];
        acc0 = fmaf(d, bf_lo(u), acc0);
        acc1 = fmaf(d, bf_hi(u), acc1);
    }
    if (k < end && half == 0) {
        int j = adj[k];
        float d = dis[j];
        unsigned int u = hsu[(size_t)j * 32 + c2];
        acc0 = fmaf(d, bf_lo(u), acc0);
        acc1 = fmaf(d, bf_hi(u), acc1);
    }
    acc0 += __shfl_xor(acc0, 32);
    acc1 += __shfl_xor(acc1, 32);
    float d = dis[node];
    unsigned int us = hsu[(size_t)node * 32 + c2];
    acc0 = fmaf(d, bf_lo(us), acc0);   // self loop: dis_i * hu_i
    acc1 = fmaf(d, bf_hi(us), acc1);
    if (half == 0) {
        float2 r;
        r.x = fmaxf(d * acc0, 0.0f);
        r.y = fmaxf(d * acc1, 0.0f);
        *reinterpret_cast<float2*>(out1 + (size_t)node * 64 + 2 * c2) = r;
    }
}

// ---------------------------------------------------------------------------
// GEMM2 via MFMA: h2s_bf16[N][40] = bf16((out1[N][64] @ W2[64][40] + b2)*dis).
// ---------------------------------------------------------------------------
__global__ __launch_bounds__(256) void k_gemm2_mfma(const float* __restrict__ A,
                                                    const float* __restrict__ W2,
                                                    const float* __restrict__ b2,
                                                    const float* __restrict__ dis,
                                                    unsigned short* __restrict__ h2sb,
                                                    int N) {
    __shared__ unsigned short sWhi[48 * WK2];
    __shared__ unsigned short sWlo[48 * WK2];
    for (int i = threadIdx.x; i < 48 * 64; i += 256) {
        int c = i >> 6;      // 0..47
        int k = i & 63;      // 0..63
        float w = (c < 40) ? W2[(size_t)k * 40 + c] : 0.0f;
        unsigned int hb = cvt_pk_bf16(w, 0.0f) & 0xffffu;
        float hf = __uint_as_float(hb << 16);
        unsigned int lb = cvt_pk_bf16(w - hf, 0.0f) & 0xffffu;
        sWhi[c * WK2 + k] = (unsigned short)hb;
        sWlo[c * WK2 + k] = (unsigned short)lb;
    }
    __syncthreads();

    const int lane = threadIdx.x & 63;
    const int wid  = threadIdx.x >> 6;
    const int ridx = lane & 15;
    const int kgrp = lane >> 4;
    const int r0 = blockIdx.x * 128 + wid * 32;
    if (r0 >= N) return;

    f32x4 acc[2][3] = {};

    #pragma unroll
    for (int ks = 0; ks < 2; ++ks) {
        const int ka = ks * 32 + kgrp * 8;
        int ra0 = min(r0 + ridx, N - 1);
        int ra1 = min(r0 + 16 + ridx, N - 1);
        const float4* pa0 = (const float4*)(A + (size_t)ra0 * 64 + ka);
        const float4* pa1 = (const float4*)(A + (size_t)ra1 * 64 + ka);
        float4 a0a = pa0[0], a0b = pa0[1];
        float4 a1a = pa1[0], a1b = pa1[1];
        bf16x8 a0hi, a0lo, a1hi, a1lo;
        make_frags(a0a, a0b, a0hi, a0lo);
        make_frags(a1a, a1b, a1hi, a1lo);
        #pragma unroll
        for (int ct = 0; ct < 3; ++ct) {
            const int cbase = (ct * 16 + ridx) * WK2 + ka;
            bf16x8 bh = ld_frag(sWhi + cbase);
            bf16x8 bl = ld_frag(sWlo + cbase);
            acc[0][ct] = __builtin_amdgcn_mfma_f32_16x16x32_bf16(a0hi, bh, acc[0][ct], 0, 0, 0);
            acc[0][ct] = __builtin_amdgcn_mfma_f32_16x16x32_bf16(a0lo, bh, acc[0][ct], 0, 0, 0);
            acc[0][ct] = __builtin_amdgcn_mfma_f32_16x16x32_bf16(a0hi, bl, acc[0][ct], 0, 0, 0);
            acc[1][ct] = __builtin_amdgcn_mfma_f32_16x16x32_bf16(a1hi, bh, acc[1][ct], 0, 0, 0);
            acc[1][ct] = __builtin_amdgcn_mfma_f32_16x16x32_bf16(a1lo, bh, acc[1][ct], 0, 0, 0);
            acc[1][ct] = __builtin_amdgcn_mfma_f32_16x16x32_bf16(a1hi, bl, acc[1][ct], 0, 0, 0);
        }
    }

    float bias[3];
    #pragma unroll
    for (int ct = 0; ct < 3; ++ct) {
        int c = ct * 16 + ridx;
        bias[ct] = (c < 40) ? b2[c] : 0.0f;
    }

    #pragma unroll
    for (int rt = 0; rt < 2; ++rt) {
        int rb = r0 + rt * 16 + kgrp * 4;
        #pragma unroll
        for (int reg = 0; reg < 4; ++reg) {
            int r = rb + reg;
            if (r < N) {
                float dv = dis[r];
                #pragma unroll
                for (int ct = 0; ct < 3; ++ct) {
                    int c = ct * 16 + ridx;
                    if (c < 40) {
                        float v = (acc[rt][ct][reg] + bias[ct]) * dv;
                        h2sb[(size_t)r * 40 + c] =
                            (unsigned short)(cvt_pk_bf16(v, 0.0f) & 0xffffu);
                    }
                }
            }
        }
    }
}

// out2[i][c] = dis[i]*(h2s[i][c] + sum_j h2s[j][c]); bf16 rows (20 uints).
// 3 neighbor-groups x 20 channels = 60 active lanes; cross-group shfl reduce.
__global__ __launch_bounds__(256) void k_gather40(const unsigned int* __restrict__ h2u,
                                                  const unsigned short* __restrict__ adj,
                                                  const int* __restrict__ offs,
                                                  const int* __restrict__ ends,
                                                  const float* __restrict__ dis,
                                                  float* __restrict__ out, int N) {
    int node = (blockIdx.x * 256 + threadIdx.x) >> 6;
    if (node >= N) return;
    int lane = threadIdx.x & 63;
    int g = lane / 20;           // 0..2 active, 3 = idle
    int c = lane - g * 20;       // 0..19
    bool act = g < 3;
    int k   = offs[node];
    int end = ends[node];
    float acc0 = 0.f, acc1 = 0.f;
    for (; k + 6 <= end; k += 6) {
        if (act) {
            int ja = adj[k + g];
            int jb = adj[k + 3 + g];
            unsigned int ua = h2u[(size_t)ja * 20 + c];
            unsigned int ub = h2u[(size_t)jb * 20 + c];
            acc0 += bf_lo(ua) + bf_lo(ub);
            acc1 += bf_hi(ua) + bf_hi(ub);
        }
    }
    for (; k + 3 <= end; k += 3) {
        if (act) {
            int j = adj[k + g];
            unsigned int u = h2u[(size_t)j * 20 + c];
            acc0 += bf_lo(u);
            acc1 += bf_hi(u);
        }
    }
    int rem = end - k;           // 0..2
    if (act && g < rem) {
        int j = adj[k + g];
        unsigned int u = h2u[(size_t)j * 20 + c];
        acc0 += bf_lo(u);
        acc1 += bf_hi(u);
    }
    // reduce groups 1,2 into group 0 (lanes 0..19)
    acc0 += __shfl(acc0, lane + 20) + __shfl(acc0, lane + 40);
    acc1 += __shfl(acc1, lane + 20) + __shfl(acc1, lane + 40);
    if (lane < 20) {
        unsigned int us = h2u[(size_t)node * 20 + c];
        float d = dis[node];
        float2 r;
        r.x = d * (acc0 + bf_lo(us));
        r.y = d * (acc1 + bf_hi(us));
        *reinterpret_cast<float2*>(out + (size_t)node * 40 + 2 * c) = r;
    }
}

extern "C" void kernel_launch(void* const* d_in, const int* in_sizes, int n_in,
                              void* d_out, int out_size, void* d_ws, size_t ws_size,
                              hipStream_t stream) {
    const float* X  = (const float*)d_in[0];
    const float* W1 = (const float*)d_in[1];
    const float* b1 = (const float*)d_in[2];
    const float* W2 = (const float*)d_in[3];
    const float* b2 = (const float*)d_in[4];
    const int*   ei = (const int*)d_in[5];

    const int Chid = in_sizes[2];            // 64
    const int Cin  = in_sizes[1] / Chid;     // 128
    const int N    = in_sizes[0] / Cin;      // 50000
    const int E    = in_sizes[5] / 2;        // 800000

    const int* src = ei;
    const int* dst = ei + E;

    const int nbuck = (N + 63) >> BUCK_SHIFT;   // 782
    const int chunk = (E + B1 - 1) / B1;        // 3125 (<= 4*BT)
    const size_t slots = (size_t)nbuck * CAP;   // 3.2M padded slots

    // ---- workspace layout (~26.5 MB) ----
    auto align256 = [](size_t x) { return (x + 255) & ~(size_t)255; };
    char* p = (char*)d_ws;
    int*   cursors = (int*)p; p += align256((size_t)nbuck * 4);
    float* dis     = (float*)p; p += align256((size_t)N * 4);
    int*   offs    = (int*)p; p += align256((size_t)N * 4);
    int*   ends    = (int*)p; p += align256((size_t)N * 4);
    unsigned short* adj = (unsigned short*)p; p += align256(slots * 2);
    unsigned int* binned = (unsigned int*)p; p += align256(slots * 4);
    unsigned int* h2u    = binned;                       // overlay (post-reorder)
    unsigned short* hub  = (unsigned short*)p;           // N*64 bf16 (6.4MB)

    float* out1 = (float*)d_out;             // N*64
    float* out2 = out1 + (size_t)N * 64;     // N*40

    hipMemsetAsync(cursors, 0, (size_t)nbuck * 4, stream);

    const int gemmBlocks = (N + GROWS - 1) / GROWS;   // 98
    k_build_gemm1<<<B1 + gemmBlocks, BT, 0, stream>>>(src, dst, cursors, binned,
                                                      X, W1, b1, hub,
                                                      E, nbuck, chunk, N);
    k_reorder<<<nbuck, 256, 0, stream>>>(binned, cursors, adj, offs, ends, dis,
                                         N, nbuck);
    k_gather64<<<(N + 3) / 4, 256, 0, stream>>>((const unsigned int*)hub, adj,
                                                offs, ends, dis, out1, N);
    k_gemm2_mfma<<<(N + 127) / 128, 256, 0, stream>>>(out1, W2, b2, dis,
                                                      (unsigned short*)h2u, N);
    k_gather40<<<(N + 3) / 4, 256, 0, stream>>>(h2u, adj, offs, ends, dis, out2, N);
}

// Round 15
// 121.054 us; speedup vs baseline: 1.0304x; 1.0304x over previous
//
#include <hip/hip_runtime.h>

// ---------------------------------------------------------------------------
// GCN 2-layer forward, 6 dispatches:
//   memset        : cursors = 0
//   k_build_gemm1 : 1024 thr/block. blocks [0,B1) = bucket binning via LDS
//                   MULTISPLIT (hist -> scan -> LDS-sorted staging -> coalesced
//                   copy-out); blocks [B1,..) = MFMA gemm1,
//                   hu_bf16 = bf16(X@W1 + b1)  (UNSCALED -> no build dep)
//   k_reorder     : per-bucket LDS sort -> padded CSR, binned register-cached
//   k_gather64    : out1 = relu(dis_i*(dis_i*hu_i + sum_j dis_j*hu_j))
//   k_gemm2_mfma  : h2s_bf16 = bf16((out1@W2 + b2)*dis)
//   k_gather40    : out2 = dis_i*(h2s_i + sum_j h2s_j)  (60-lane, 3 groups)
// ---------------------------------------------------------------------------

#define B1 256          // build blocks
#define BT 1024         // build/gemm1 merged kernel block size
#define GROWS 512       // gemm1 rows per block (16 waves x 32 rows)
#define BUCK_SHIFT 6    // 64 nodes per bucket
#define CAP 4096        // padded slots per bucket (fill ~2250 max)
#define STAGE 8192      // build LDS staging entries (2*chunk <= 8192)
#define WK 136          // gemm1 LDS K stride (ushorts)
#define WK2 72          // gemm2 LDS K stride (ushorts)

typedef float f32x4 __attribute__((ext_vector_type(4)));
typedef short bf16x8 __attribute__((ext_vector_type(8)));

union Frag { unsigned int u[4]; bf16x8 v; };

__device__ __forceinline__ unsigned int cvt_pk_bf16(float a, float b) {
    unsigned int r;
    asm("v_cvt_pk_bf16_f32 %0, %1, %2" : "=v"(r) : "v"(a), "v"(b));
    return r;  // low16 = bf16(a), high16 = bf16(b), RNE
}

__device__ __forceinline__ float bf_lo(unsigned int u) {
    return __uint_as_float(u << 16);
}
__device__ __forceinline__ float bf_hi(unsigned int u) {
    return __uint_as_float(u & 0xffff0000u);
}

__device__ __forceinline__ bf16x8 ld_frag(const unsigned short* p) {
    uint4 t = *reinterpret_cast<const uint4*>(p);
    Frag f; f.u[0] = t.x; f.u[1] = t.y; f.u[2] = t.z; f.u[3] = t.w;
    return f.v;
}

__device__ __forceinline__ void make_frags(const float4 a, const float4 b,
                                           bf16x8& hi8, bf16x8& lo8) {
    Frag hi, lo;
    hi.u[0] = cvt_pk_bf16(a.x, a.y);
    hi.u[1] = cvt_pk_bf16(a.z, a.w);
    hi.u[2] = cvt_pk_bf16(b.x, b.y);
    hi.u[3] = cvt_pk_bf16(b.z, b.w);
    lo.u[0] = cvt_pk_bf16(a.x - __uint_as_float(hi.u[0] << 16),
                          a.y - __uint_as_float(hi.u[0] & 0xffff0000u));
    lo.u[1] = cvt_pk_bf16(a.z - __uint_as_float(hi.u[1] << 16),
                          a.w - __uint_as_float(hi.u[1] & 0xffff0000u));
    lo.u[2] = cvt_pk_bf16(b.x - __uint_as_float(hi.u[2] << 16),
                          b.y - __uint_as_float(hi.u[2] & 0xffff0000u));
    lo.u[3] = cvt_pk_bf16(b.z - __uint_as_float(hi.u[3] << 16),
                          b.w - __uint_as_float(hi.u[3] & 0xffff0000u));
    hi8 = hi.v; lo8 = lo.v;
}

// ---------------------------------------------------------------------------
// Merged build + gemm1, 1024 threads.
// Build LDS: lh[1024] + lscan[1024] + sbuf[1024] + lbase[1024] + stage[8192]
//          = 16KB + 32KB = 48KB.  Gemm1 LDS: 34.8KB.  Union: 48KB (2 blk/CU,
//          wave-capped anyway).
// ---------------------------------------------------------------------------
__global__ __launch_bounds__(BT) void k_build_gemm1(
        const int* __restrict__ src, const int* __restrict__ dst,
        int* __restrict__ cursors, unsigned int* __restrict__ binned,
        const float* __restrict__ X, const float* __restrict__ W1,
        const float* __restrict__ b1, unsigned short* __restrict__ hub,
        int E, int nbuck, int chunk, int N) {
    __shared__ __align__(16) char smem[49152];

    if (blockIdx.x < B1) {
        // ---------------- build path: LDS multisplit ----------------
        int* lh    = (int*)smem;              // [1024] hist -> local cursor
        int* lscan = lh + 1024;               // [1024] exclusive scan
        int* sbuf  = lscan + 1024;            // [1024] scan ping buffer
        int* lbase = sbuf + 1024;             // [1024] global run base
        unsigned int* stage = (unsigned int*)(lbase + 1024);  // [STAGE]

        const int t = threadIdx.x;            // 0..1023
        lh[t] = 0;
        __syncthreads();

        int e0 = blockIdx.x * chunk;
        int e1 = min(e0 + chunk, E);
        // register-cache up to 4 edges/thread (chunk <= 4*BT)
        int es[4], eds[4];
        #pragma unroll
        for (int i = 0; i < 4; ++i) {
            int e = e0 + t + i * BT;
            if (e < e1) {
                int s = src[e], d = dst[e];
                es[i] = s; eds[i] = d;
                atomicAdd(&lh[s >> BUCK_SHIFT], 1);
                atomicAdd(&lh[d >> BUCK_SHIFT], 1);
            }
        }
        __syncthreads();

        // exclusive scan of lh[0..1023] (one element per thread)
        int cntv = lh[t];
        int* bufA = sbuf; int* bufB = lscan;
        bufA[t] = cntv;
        __syncthreads();
        #pragma unroll
        for (int w = 1; w < 1024; w <<= 1) {
            int x = bufA[t];
            if (t >= w) x += bufA[t - w];
            bufB[t] = x;
            __syncthreads();
            int* tmp = bufA; bufA = bufB; bufB = tmp;
        }
        int excl = bufA[t] - cntv;   // bufA == sbuf after 10 swaps
        lscan[t] = excl;             // lscan == bufB, contents dead
        int rel = (t < nbuck && cntv > 0) ? atomicAdd(&cursors[t], cntv) : 0;
        lbase[t] = t * CAP + rel;
        lh[t] = excl;                // reuse as local staging cursor
        __syncthreads();

        // scatter entries into LDS staging, sorted by bucket
        #pragma unroll
        for (int i = 0; i < 4; ++i) {
            int e = e0 + t + i * BT;
            if (e < e1) {
                unsigned int s = (unsigned int)es[i];
                unsigned int d = (unsigned int)eds[i];
                int ps = atomicAdd(&lh[s >> BUCK_SHIFT], 1);
                stage[ps] = (s << 16) | d;
                int pd = atomicAdd(&lh[d >> BUCK_SHIFT], 1);
                stage[pd] = (d << 16) | s;
            }
        }
        __syncthreads();

        // coalesced copy-out: run of bucket b -> binned[lbase[b] + (i-lscan[b])]
        int total = 2 * (e1 - e0);
        for (int i = t; i < total; i += BT) {
            unsigned int v = stage[i];
            int b = (v >> 16) >> BUCK_SHIFT;
            int gpos = lbase[b] + (i - lscan[b]);
            if (gpos < ((b + 1) << 12)) binned[gpos] = v;
        }
        return;
    }

    // ---------------- gemm1 path (split-bf16 MFMA, unscaled) ----------------
    unsigned short* sWhi = (unsigned short*)smem;
    unsigned short* sWlo = sWhi + 64 * WK;
    for (int i = threadIdx.x; i < 128 * 64; i += BT) {
        int c = i >> 7;      // 0..63
        int k = i & 127;     // 0..127
        float w = W1[(size_t)k * 64 + c];
        unsigned int hb = cvt_pk_bf16(w, 0.0f) & 0xffffu;
        float hf = __uint_as_float(hb << 16);
        unsigned int lb = cvt_pk_bf16(w - hf, 0.0f) & 0xffffu;
        sWhi[c * WK + k] = (unsigned short)hb;
        sWlo[c * WK + k] = (unsigned short)lb;
    }
    __syncthreads();

    const int lane = threadIdx.x & 63;
    const int wid  = threadIdx.x >> 6;      // 0..15
    const int ridx = lane & 15;
    const int kgrp = lane >> 4;
    const int r0 = (blockIdx.x - B1) * GROWS + wid * 32;

    f32x4 acc[2][4] = {};

    #pragma unroll
    for (int ks = 0; ks < 4; ++ks) {
        const int ka = ks * 32 + kgrp * 8;
        int ra0 = min(r0 + ridx, N - 1);
        int ra1 = min(r0 + 16 + ridx, N - 1);
        const float4* pa0 = (const float4*)(X + (size_t)ra0 * 128 + ka);
        const float4* pa1 = (const float4*)(X + (size_t)ra1 * 128 + ka);
        float4 a0a = pa0[0], a0b = pa0[1];
        float4 a1a = pa1[0], a1b = pa1[1];
        bf16x8 a0hi, a0lo, a1hi, a1lo;
        make_frags(a0a, a0b, a0hi, a0lo);
        make_frags(a1a, a1b, a1hi, a1lo);
        #pragma unroll
        for (int ct = 0; ct < 4; ++ct) {
            const int cbase = (ct * 16 + ridx) * WK + ka;
            bf16x8 bh = ld_frag(sWhi + cbase);
            bf16x8 bl = ld_frag(sWlo + cbase);
            acc[0][ct] = __builtin_amdgcn_mfma_f32_16x16x32_bf16(a0hi, bh, acc[0][ct], 0, 0, 0);
            acc[0][ct] = __builtin_amdgcn_mfma_f32_16x16x32_bf16(a0lo, bh, acc[0][ct], 0, 0, 0);
            acc[0][ct] = __builtin_amdgcn_mfma_f32_16x16x32_bf16(a0hi, bl, acc[0][ct], 0, 0, 0);
            acc[1][ct] = __builtin_amdgcn_mfma_f32_16x16x32_bf16(a1hi, bh, acc[1][ct], 0, 0, 0);
            acc[1][ct] = __builtin_amdgcn_mfma_f32_16x16x32_bf16(a1lo, bh, acc[1][ct], 0, 0, 0);
            acc[1][ct] = __builtin_amdgcn_mfma_f32_16x16x32_bf16(a1hi, bl, acc[1][ct], 0, 0, 0);
        }
    }

    float bias[4];
    #pragma unroll
    for (int ct = 0; ct < 4; ++ct) bias[ct] = b1[ct * 16 + ridx];

    #pragma unroll
    for (int rt = 0; rt < 2; ++rt) {
        int rb = r0 + rt * 16 + kgrp * 4;
        #pragma unroll
        for (int reg = 0; reg < 4; ++reg) {
            int r = rb + reg;
            if (r < N) {
                #pragma unroll
                for (int ct = 0; ct < 4; ++ct) {
                    float v = acc[rt][ct][reg] + bias[ct];
                    hub[(size_t)r * 64 + ct * 16 + ridx] =
                        (unsigned short)(cvt_pk_bf16(v, 0.0f) & 0xffffu);
                }
            }
        }
    }
}

// Per-bucket: binned -> node-grouped ushort adj; binned register-cached
// (single global read). offs/ends absolute, dis = rsqrt(1+deg).
__global__ __launch_bounds__(256) void k_reorder(const unsigned int* __restrict__ binned,
                                                 const int* __restrict__ cursors,
                                                 unsigned short* __restrict__ adj,
                                                 int* __restrict__ offs,
                                                 int* __restrict__ ends,
                                                 float* __restrict__ dis,
                                                 int N, int nbuck) {
    __shared__ int cnt[64];
    __shared__ int cur[64];
    __shared__ unsigned short stage[CAP];
    int b = blockIdx.x;
    int start = b * CAP;
    int fill = cursors[b]; if (fill > CAP) fill = CAP;
    int end = start + fill;
    if (threadIdx.x < 64) cnt[threadIdx.x] = 0;
    __syncthreads();
    // register-cache: CAP/256 = 16 entries max per thread, static unroll
    unsigned int vv[16];
    #pragma unroll
    for (int i = 0; i < 16; ++i) {
        int idx = start + threadIdx.x + i * 256;
        if (idx < end) {
            unsigned int v = binned[idx];
            vv[i] = v;
            atomicAdd(&cnt[(v >> 16) & 63], 1);
        }
    }
    __syncthreads();
    if (threadIdx.x == 0) {
        int run = 0;
        for (int l = 0; l < 64; ++l) { cur[l] = run; run += cnt[l]; }
    }
    __syncthreads();
    if (threadIdx.x < 64) {
        int node = (b << BUCK_SHIFT) + threadIdx.x;
        if (node < N) {
            int o = start + cur[threadIdx.x];
            offs[node] = o;
            ends[node] = o + cnt[threadIdx.x];
            dis[node]  = rsqrtf(1.0f + (float)cnt[threadIdx.x]);
        }
    }
    __syncthreads();
    #pragma unroll
    for (int i = 0; i < 16; ++i) {
        int idx = start + threadIdx.x + i * 256;
        if (idx < end) {
            unsigned int v = vv[i];
            int nl = (v >> 16) & 63;
            int p = atomicAdd(&cur[nl], 1);
            stage[p] = (unsigned short)(v & 0xffffu);
        }
    }
    __syncthreads();
    for (int i = threadIdx.x; i < fill; i += 256)
        adj[start + i] = stage[i];
}

// out1_i = relu(dis_i*(dis_i*hu_i + sum_j dis_j*hu_j)); wave per node.
__global__ __launch_bounds__(256) void k_gather64(const unsigned int* __restrict__ hsu,
                                                  const unsigned short* __restrict__ adj,
                                                  const int* __restrict__ offs,
                                                  const int* __restrict__ ends,
                                                  const float* __restrict__ dis,
                                                  float* __restrict__ out1, int N) {
    int node = (blockIdx.x * 256 + threadIdx.x) >> 6;
    if (node >= N) return;
    int lane = threadIdx.x & 63;
    int half = lane >> 5;
    int c2 = lane & 31;
    int k   = offs[node];
    int end = ends[node];
    float acc0 = 0.f, acc1 = 0.f;
    for (; k + 16 <= end; k += 16) {
        int j0 = adj[k +  0 + half], j1 = adj[k +  2 + half];
        int j2 = adj[k +  4 + half], j3 = adj[k +  6 + half];
        int j4 = adj[k +  8 + half], j5 = adj[k + 10 + half];
        int j6 = adj[k + 12 + half], j7 = adj[k + 14 + half];
        float d0 = dis[j0], d1 = dis[j1], d2 = dis[j2], d3 = dis[j3];
        float d4 = dis[j4], d5 = dis[j5], d6 = dis[j6], d7 = dis[j7];
        unsigned int u0 = hsu[(size_t)j0 * 32 + c2];
        unsigned int u1 = hsu[(size_t)j1 * 32 + c2];
        unsigned int u2 = hsu[(size_t)j2 * 32 + c2];
        unsigned int u3 = hsu[(size_t)j3 * 32 + c2];
        unsigned int u4 = hsu[(size_t)j4 * 32 + c2];
        unsigned int u5 = hsu[(size_t)j5 * 32 + c2];
        unsigned int u6 = hsu[(size_t)j6 * 32 + c2];
        unsigned int u7 = hsu[(size_t)j7 * 32 + c2];
        acc0 = fmaf(d0, bf_lo(u0), acc0); acc1 = fmaf(d0, bf_hi(u0), acc1);
        acc0 = fmaf(d1, bf_lo(u1), acc0); acc1 = fmaf(d1, bf_hi(u1), acc1);
        acc0 = fmaf(d2, bf_lo(u2), acc0); acc1 = fmaf(d2, bf_hi(u2), acc1);
        acc0 = fmaf(d3, bf_lo(u3), acc0); acc1 = fmaf(d3, bf_hi(u3), acc1);
        acc0 = fmaf(d4, bf_lo(u4), acc0); acc1 = fmaf(d4, bf_hi(u4), acc1);
        acc0 = fmaf(d5, bf_lo(u5), acc0); acc1 = fmaf(d5, bf_hi(u5), acc1);
        acc0 = fmaf(d6, bf_lo(u6), acc0); acc1 = fmaf(d6, bf_hi(u6), acc1);
        acc0 = fmaf(d7, bf_lo(u7), acc0); acc1 = fmaf(d7, bf_hi(u7), acc1);
    }
    for (; k + 8 <= end; k += 8) {
        int j0 = adj[k + 0 + half], j1 = adj[k + 2 + half];
        int j2 = adj[k + 4 + half], j3 = adj[k + 6 + half];
        float d0 = dis[j0], d1 = dis[j1], d2 = dis[j2], d3 = dis[j3];
        unsigned int u0 = hsu[(size_t)j0 * 32 + c2];
        unsigned int u1 = hsu[(size_t)j1 * 32 + c2];
        unsigned int u2 = hsu[(size_t)j2 * 32 + c2];
        unsigned int u3 = hsu[(size_t)j3 * 32 + c2];
        acc0 = fmaf(d0, bf_lo(u0), acc0); acc1 = fmaf(d0, bf_hi(u0), acc1);
        acc0 = fmaf(d1, bf_lo(u1), acc0); acc1 = fmaf(d1, bf_hi(u1), acc1);
        acc0 = fmaf(d2, bf_lo(u2), acc0); acc1 = fmaf(d2, bf_hi(u2), acc1);
        acc0 = fmaf(d3, bf_lo(u3), acc0); acc1 = fmaf(d3, bf_hi(u3), acc1);
    }
    for (; k + 2 <= end; k += 2) {
        int j = adj[k + half];
        float d = dis[j];
        unsigned int u = hsu[(size_t)j * 32 + c2];
        acc0 = fmaf(d, bf_lo(u), acc0);
        acc1 = fmaf(d, bf_hi(u), acc1);
    }
    if (k < end && half == 0) {
        int j = adj[k];
        float d = dis[j];
        unsigned int u = hsu[(size_t)j * 32 + c2];
        acc0 = fmaf(d, bf_lo(u), acc0);
        acc1 = fmaf(d, bf_hi(u), acc1);
    }
    acc0 += __shfl_xor(acc0, 32);
    acc1 += __shfl_xor(acc1, 32);
    float d = dis[node];
    unsigned int us = hsu[(size_t)node * 32 + c2];
    acc0 = fmaf(d, bf_lo(us), acc0);   // self loop: dis_i * hu_i
    acc1 = fmaf(d, bf_hi(us), acc1);
    if (half == 0) {
        float2 r;
        r.x = fmaxf(d * acc0, 0.0f);
        r.y = fmaxf(d * acc1, 0.0f);
        *reinterpret_cast<float2*>(out1 + (size_t)node * 64 + 2 * c2) = r;
    }
}

// ---------------------------------------------------------------------------
// GEMM2 via MFMA: h2s_bf16[N][40] = bf16((out1[N][64] @ W2[64][40] + b2)*dis).
// ---------------------------------------------------------------------------
__global__ __launch_bounds__(256) void k_gemm2_mfma(const float* __restrict__ A,
                                                    const float* __restrict__ W2,
                                                    const float* __restrict__ b2,
                                                    const float* __restrict__ dis,
                                                    unsigned short* __restrict__ h2sb,
                                                    int N) {
    __shared__ unsigned short sWhi[48 * WK2];
    __shared__ unsigned short sWlo[48 * WK2];
    for (int i = threadIdx.x; i < 48 * 64; i += 256) {
        int c = i >> 6;      // 0..47
        int k = i & 63;      // 0..63
        float w = (c < 40) ? W2[(size_t)k * 40 + c] : 0.0f;
        unsigned int hb = cvt_pk_bf16(w, 0.0f) & 0xffffu;
        float hf = __uint_as_float(hb << 16);
        unsigned int lb = cvt_pk_bf16(w - hf, 0.0f) & 0xffffu;
        sWhi[c * WK2 + k] = (unsigned short)hb;
        sWlo[c * WK2 + k] = (unsigned short)lb;
    }
    __syncthreads();

    const int lane = threadIdx.x & 63;
    const int wid  = threadIdx.x >> 6;
    const int ridx = lane & 15;
    const int kgrp = lane >> 4;
    const int r0 = blockIdx.x * 128 + wid * 32;
    if (r0 >= N) return;

    f32x4 acc[2][3] = {};

    #pragma unroll
    for (int ks = 0; ks < 2; ++ks) {
        const int ka = ks * 32 + kgrp * 8;
        int ra0 = min(r0 + ridx, N - 1);
        int ra1 = min(r0 + 16 + ridx, N - 1);
        const float4* pa0 = (const float4*)(A + (size_t)ra0 * 64 + ka);
        const float4* pa1 = (const float4*)(A + (size_t)ra1 * 64 + ka);
        float4 a0a = pa0[0], a0b = pa0[1];
        float4 a1a = pa1[0], a1b = pa1[1];
        bf16x8 a0hi, a0lo, a1hi, a1lo;
        make_frags(a0a, a0b, a0hi, a0lo);
        make_frags(a1a, a1b, a1hi, a1lo);
        #pragma unroll
        for (int ct = 0; ct < 3; ++ct) {
            const int cbase = (ct * 16 + ridx) * WK2 + ka;
            bf16x8 bh = ld_frag(sWhi + cbase);
            bf16x8 bl = ld_frag(sWlo + cbase);
            acc[0][ct] = __builtin_amdgcn_mfma_f32_16x16x32_bf16(a0hi, bh, acc[0][ct], 0, 0, 0);
            acc[0][ct] = __builtin_amdgcn_mfma_f32_16x16x32_bf16(a0lo, bh, acc[0][ct], 0, 0, 0);
            acc[0][ct] = __builtin_amdgcn_mfma_f32_16x16x32_bf16(a0hi, bl, acc[0][ct], 0, 0, 0);
            acc[1][ct] = __builtin_amdgcn_mfma_f32_16x16x32_bf16(a1hi, bh, acc[1][ct], 0, 0, 0);
            acc[1][ct] = __builtin_amdgcn_mfma_f32_16x16x32_bf16(a1lo, bh, acc[1][ct], 0, 0, 0);
            acc[1][ct] = __builtin_amdgcn_mfma_f32_16x16x32_bf16(a1hi, bl, acc[1][ct], 0, 0, 0);
        }
    }

    float bias[3];
    #pragma unroll
    for (int ct = 0; ct < 3; ++ct) {
        int c = ct * 16 + ridx;
        bias[ct] = (c < 40) ? b2[c] : 0.0f;
    }

    #pragma unroll
    for (int rt = 0; rt < 2; ++rt) {
        int rb = r0 + rt * 16 + kgrp * 4;
        #pragma unroll
        for (int reg = 0; reg < 4; ++reg) {
            int r = rb + reg;
            if (r < N) {
                float dv = dis[r];
                #pragma unroll
                for (int ct = 0; ct < 3; ++ct) {
                    int c = ct * 16 + ridx;
                    if (c < 40) {
                        float v = (acc[rt][ct][reg] + bias[ct]) * dv;
                        h2sb[(size_t)r * 40 + c] =
                            (unsigned short)(cvt_pk_bf16(v, 0.0f) & 0xffffu);
                    }
                }
            }
        }
    }
}

// out2[i][c] = dis[i]*(h2s[i][c] + sum_j h2s[j][c]); bf16 rows (20 uints).
// 3 neighbor-groups x 20 channels = 60 active lanes; cross-group shfl reduce.
__global__ __launch_bounds__(256) void k_gather40(const unsigned int* __restrict__ h2u,
                                                  const unsigned short* __restrict__ adj,
                                                  const int* __restrict__ offs,
                                                  const int* __restrict__ ends,
                                                  const float* __restrict__ dis,
                                                  float* __restrict__ out, int N) {
    int node = (blockIdx.x * 256 + threadIdx.x) >> 6;
    if (node >= N) return;
    int lane = threadIdx.x & 63;
    int g = lane / 20;           // 0..2 active, 3 = idle
    int c = lane - g * 20;       // 0..19
    bool act = g < 3;
    int k   = offs[node];
    int end = ends[node];
    float acc0 = 0.f, acc1 = 0.f;
    for (; k + 6 <= end; k += 6) {
        if (act) {
            int ja = adj[k + g];
            int jb = adj[k + 3 + g];
            unsigned int ua = h2u[(size_t)ja * 20 + c];
            unsigned int ub = h2u[(size_t)jb * 20 + c];
            acc0 += bf_lo(ua) + bf_lo(ub);
            acc1 += bf_hi(ua) + bf_hi(ub);
        }
    }
    for (; k + 3 <= end; k += 3) {
        if (act) {
            int j = adj[k + g];
            unsigned int u = h2u[(size_t)j * 20 + c];
            acc0 += bf_lo(u);
            acc1 += bf_hi(u);
        }
    }
    int rem = end - k;           // 0..2
    if (act && g < rem) {
        int j = adj[k + g];
        unsigned int u = h2u[(size_t)j * 20 + c];
        acc0 += bf_lo(u);
        acc1 += bf_hi(u);
    }
    // reduce groups 1,2 into group 0 (lanes 0..19)
    acc0 += __shfl(acc0, lane + 20) + __shfl(acc0, lane + 40);
    acc1 += __shfl(acc1, lane + 20) + __shfl(acc1, lane + 40);
    if (lane < 20) {
        unsigned int us = h2u[(size_t)node * 20 + c];
        float d = dis[node];
        float2 r;
        r.x = d * (acc0 + bf_lo(us));
        r.y = d * (acc1 + bf_hi(us));
        *reinterpret_cast<float2*>(out + (size_t)node * 40 + 2 * c) = r;
    }
}

extern "C" void kernel_launch(void* const* d_in, const int* in_sizes, int n_in,
                              void* d_out, int out_size, void* d_ws, size_t ws_size,
                              hipStream_t stream) {
    const float* X  = (const float*)d_in[0];
    const float* W1 = (const float*)d_in[1];
    const float* b1 = (const float*)d_in[2];
    const float* W2 = (const float*)d_in[3];
    const float* b2 = (const float*)d_in[4];
    const int*   ei = (const int*)d_in[5];

    const int Chid = in_sizes[2];            // 64
    const int Cin  = in_sizes[1] / Chid;     // 128
    const int N    = in_sizes[0] / Cin;      // 50000
    const int E    = in_sizes[5] / 2;        // 800000

    const int* src = ei;
    const int* dst = ei + E;

    const int nbuck = (N + 63) >> BUCK_SHIFT;   // 782
    const int chunk = (E + B1 - 1) / B1;        // 3125 (<= 4*BT, 2*chunk <= STAGE)
    const size_t slots = (size_t)nbuck * CAP;   // 3.2M padded slots

    // ---- workspace layout (~26.5 MB) ----
    auto align256 = [](size_t x) { return (x + 255) & ~(size_t)255; };
    char* p = (char*)d_ws;
    int*   cursors = (int*)p; p += align256((size_t)nbuck * 4);
    float* dis     = (float*)p; p += align256((size_t)N * 4);
    int*   offs    = (int*)p; p += align256((size_t)N * 4);
    int*   ends    = (int*)p; p += align256((size_t)N * 4);
    unsigned short* adj = (unsigned short*)p; p += align256(slots * 2);
    unsigned int* binned = (unsigned int*)p; p += align256(slots * 4);
    unsigned int* h2u    = binned;                       // overlay (post-reorder)
    unsigned short* hub  = (unsigned short*)p;           // N*64 bf16 (6.4MB)

    float* out1 = (float*)d_out;             // N*64
    float* out2 = out1 + (size_t)N * 64;     // N*40

    hipMemsetAsync(cursors, 0, (size_t)nbuck * 4, stream);

    const int gemmBlocks = (N + GROWS - 1) / GROWS;   // 98
    k_build_gemm1<<<B1 + gemmBlocks, BT, 0, stream>>>(src, dst, cursors, binned,
                                                      X, W1, b1, hub,
                                                      E, nbuck, chunk, N);
    k_reorder<<<nbuck, 256, 0, stream>>>(binned, cursors, adj, offs, ends, dis,
                                         N, nbuck);
    k_gather64<<<(N + 3) / 4, 256, 0, stream>>>((const unsigned int*)hub, adj,
                                                offs, ends, dis, out1, N);
    k_gemm2_mfma<<<(N + 127) / 128, 256, 0, stream>>>(out1, W2, b2, dis,
                                                      (unsigned short*)h2u, N);
    k_gather40<<<(N + 3) / 4, 256, 0, stream>>>(h2u, adj, offs, ends, dis, out2, N);
}